// Round 1
// baseline (315.656 us; speedup 1.0000x reference)
//
#include <hip/hip_runtime.h>

#define B_ 1024
#define D_ 512
#define T_ 36
#define NT_ 64
#define DS_ 32
#define DG_ 128   // D/G
#define EPS_ 1e-5f

typedef float f32x4 __attribute__((ext_vector_type(4)));
typedef __bf16 bf16x8 __attribute__((ext_vector_type(8)));
typedef unsigned short u16x8 __attribute__((ext_vector_type(8)));

#define DEVI static __device__ __forceinline__

DEVI unsigned short f2bf(float f) {
    union { float f; unsigned u; } v; v.f = f;
    unsigned u = v.u;
    unsigned r = u + 0x7fffu + ((u >> 16) & 1u);   // RNE
    return (unsigned short)(r >> 16);
}
DEVI float bf2f(unsigned short h) {
    union { unsigned u; float f; } v; v.u = ((unsigned)h) << 16;
    return v.f;
}

// ---- K1 LDS layout (bytes) ----
// ysT/xsT ushort [64][520] @ 0       (rows s; ys/xs transposed; rows 36..63 zero)
// repb    ushort [64][520] @ 66560   (rep rows t; h overlay after G4)
// sc      float  [64][40]  @ 133120
// att1    ushort [64][72]  @ 143360  (cols 36..63 zero)
// att2    ushort [48][72]  @ 152576
// red     float  [864]     @ 159488
#define K1_LDS 162944

__global__ __launch_bounds__(512)
void k1_attn(const float* __restrict__ x, const float* __restrict__ y,
             const float* __restrict__ tok, const float* __restrict__ gav_p,
             const float* __restrict__ wd, const float* __restrict__ lnbg,
             const float* __restrict__ lnbb, float* __restrict__ z_pre)
{
    extern __shared__ char lds[];
    unsigned short* ysT  = (unsigned short*)(lds);
    unsigned short* repb = (unsigned short*)(lds + 66560);
    float*          sc   = (float*)(lds + 133120);
    unsigned short* att1 = (unsigned short*)(lds + 143360);
    unsigned short* att2 = (unsigned short*)(lds + 152576);
    float*          red  = (float*)(lds + 159488);

    const int b    = blockIdx.x;
    const int tid  = threadIdx.x;
    const int lane = tid & 63;
    const int w    = tid >> 6;   // wave 0..7
    const int l15  = lane & 15;
    const int l4   = lane >> 4;  // 0..3

    const float* yb = y + b * (D_ * T_);
    const float* xb = x + b * (D_ * T_);

    // ---- P0: zero pads, load ys transposed ----
    {
        unsigned* p = (unsigned*)(ysT + 36 * 520);
        for (int i = tid; i < (64 - 36) * 260; i += 512) p[i] = 0u;
        unsigned* q = (unsigned*)att1;
        for (int i = tid; i < 64 * 36; i += 512) q[i] = 0u;
    }
    for (int i = tid; i < D_ * T_; i += 512) {
        int d = i / T_, s = i - d * T_;
        ysT[s * 520 + d] = f2bf(yb[i]);
    }
    __syncthreads();

    // ---- G1: sc[t][s] = tok @ ys   (M=64,N=48,K=512) ----
    for (int idx = w; idx < 12; idx += 8) {
        int mt = idx & 3, nt = idx >> 2;
        f32x4 acc = {0.f, 0.f, 0.f, 0.f};
        int t = mt * 16 + l15;
        for (int ks = 0; ks < 16; ++ks) {
            int k0 = ks * 32 + l4 * 8;
            const float* ap = tok + t * 512 + k0;
            f32x4 a0 = *(const f32x4*)ap;
            f32x4 a1 = *(const f32x4*)(ap + 4);
            union { bf16x8 v; unsigned short u[8]; } af;
            af.u[0]=f2bf(a0[0]); af.u[1]=f2bf(a0[1]); af.u[2]=f2bf(a0[2]); af.u[3]=f2bf(a0[3]);
            af.u[4]=f2bf(a1[0]); af.u[5]=f2bf(a1[1]); af.u[6]=f2bf(a1[2]); af.u[7]=f2bf(a1[3]);
            bf16x8 bfv = *(const bf16x8*)&ysT[(nt * 16 + l15) * 520 + k0];
            acc = __builtin_amdgcn_mfma_f32_16x16x32_bf16(af.v, bfv, acc, 0, 0, 0);
        }
        int s = nt * 16 + l15;
        if (s < T_) {
            #pragma unroll
            for (int j = 0; j < 4; ++j)
                sc[(mt * 16 + l4 * 4 + j) * 40 + s] = acc[j];
        }
    }
    __syncthreads();

    // ---- softmax over s per t ----
    if (tid < NT_) {
        int t = tid;
        float m = -1e30f;
        for (int s = 0; s < T_; ++s) m = fmaxf(m, sc[t * 40 + s]);
        float sum = 0.f;
        for (int s = 0; s < T_; ++s) sum += __expf(sc[t * 40 + s] - m);
        float inv = 1.f / sum;
        for (int s = 0; s < T_; ++s)
            att1[t * 72 + s] = f2bf(__expf(sc[t * 40 + s] - m) * inv);
    }
    __syncthreads();

    // ---- G2: rep[t][d] = tok[t][d] + att1 @ ysT^T  (M=64,N=512,K=48->64) ----
    {
        int mt = w >> 1;
        bf16x8 a0 = *(const bf16x8*)&att1[(mt * 16 + l15) * 72 + l4 * 8];
        bf16x8 a1 = *(const bf16x8*)&att1[(mt * 16 + l15) * 72 + 32 + l4 * 8];
        int ntBase = (w & 1) * 16;
        for (int nt = ntBase; nt < ntBase + 16; ++nt) {
            int d = nt * 16 + l15;
            f32x4 acc = {0.f, 0.f, 0.f, 0.f};
            #pragma unroll
            for (int ks = 0; ks < 2; ++ks) {
                int sbase = ks * 32 + l4 * 8;
                union { bf16x8 v; unsigned short u[8]; } bfv;
                #pragma unroll
                for (int j = 0; j < 8; ++j)
                    bfv.u[j] = ysT[(sbase + j) * 520 + d];
                acc = __builtin_amdgcn_mfma_f32_16x16x32_bf16(ks ? a1 : a0, bfv.v, acc, 0, 0, 0);
            }
            #pragma unroll
            for (int j = 0; j < 4; ++j) {
                int tt = mt * 16 + l4 * 4 + j;
                repb[tt * 520 + d] = f2bf(tok[tt * 512 + d] + acc[j]);
            }
        }
    }
    __syncthreads();

    // ---- load xs transposed (overwrite ysT rows 0..35; 36..63 stay zero) ----
    for (int i = tid; i < D_ * T_; i += 512) {
        int d = i / T_, s = i - d * T_;
        ysT[s * 520 + d] = f2bf(xb[i]);
    }
    __syncthreads();

    // ---- G3: sc[t][s] = rep @ xs   (S2^T; M=64,N=48,K=512) ----
    for (int idx = w; idx < 12; idx += 8) {
        int mt = idx & 3, nt = idx >> 2;
        f32x4 acc = {0.f, 0.f, 0.f, 0.f};
        for (int ks = 0; ks < 16; ++ks) {
            int k0 = ks * 32 + l4 * 8;
            bf16x8 af  = *(const bf16x8*)&repb[(mt * 16 + l15) * 520 + k0];
            bf16x8 bfv = *(const bf16x8*)&ysT[(nt * 16 + l15) * 520 + k0];
            acc = __builtin_amdgcn_mfma_f32_16x16x32_bf16(af, bfv, acc, 0, 0, 0);
        }
        int s = nt * 16 + l15;
        if (s < T_) {
            #pragma unroll
            for (int j = 0; j < 4; ++j)
                sc[(mt * 16 + l4 * 4 + j) * 40 + s] = acc[j];
        }
    }
    __syncthreads();

    // ---- softmax over t per s ----
    if (tid < T_) {
        int s = tid;
        float m = -1e30f;
        for (int t = 0; t < NT_; ++t) m = fmaxf(m, sc[t * 40 + s]);
        float sum = 0.f;
        for (int t = 0; t < NT_; ++t) sum += __expf(sc[t * 40 + s] - m);
        float inv = 1.f / sum;
        for (int t = 0; t < NT_; ++t)
            att2[s * 72 + t] = f2bf(__expf(sc[t * 40 + s] - m) * inv);
    }
    __syncthreads();

    // ---- G4: x_res[s][d] = att2 @ rep (M=48,N=512,K=64) + xc + LN + h ----
    {
        const float gav = gav_p[0];
        f32x4 acc[3][4];
        f32x4 vzero = {0.f, 0.f, 0.f, 0.f};
        #pragma unroll
        for (int m = 0; m < 3; ++m)
            #pragma unroll
            for (int n = 0; n < 4; ++n) acc[m][n] = vzero;

        #pragma unroll
        for (int ks = 0; ks < 2; ++ks) {
            bf16x8 af[3];
            #pragma unroll
            for (int m = 0; m < 3; ++m)
                af[m] = *(const bf16x8*)&att2[(m * 16 + l15) * 72 + ks * 32 + l4 * 8];
            #pragma unroll
            for (int n = 0; n < 4; ++n) {
                int d = (4 * w + n) * 16 + l15;
                int tb = ks * 32 + l4 * 8;
                union { bf16x8 v; unsigned short u[8]; } bfv;
                #pragma unroll
                for (int j = 0; j < 8; ++j)
                    bfv.u[j] = repb[(tb + j) * 520 + d];
                #pragma unroll
                for (int m = 0; m < 3; ++m)
                    acc[m][n] = __builtin_amdgcn_mfma_f32_16x16x32_bf16(af[m], bfv.v, acc[m][n], 0, 0, 0);
            }
        }

        // xc = xs + gav*x_res ; per-s partial sums for LN
        #pragma unroll
        for (int m = 0; m < 3; ++m) {
            #pragma unroll
            for (int j = 0; j < 4; ++j) {
                int s = m * 16 + l4 * 4 + j;
                if (s < T_) {
                    float rsum = 0.f, rsq = 0.f;
                    #pragma unroll
                    for (int n = 0; n < 4; ++n) {
                        int d = (4 * w + n) * 16 + l15;
                        float xc = bf2f(ysT[s * 520 + d]) + gav * acc[m][n][j];
                        acc[m][n][j] = xc;
                        rsum += xc; rsq += xc * xc;
                    }
                    #pragma unroll
                    for (int off = 1; off < 16; off <<= 1) {
                        rsum += __shfl_xor(rsum, off);
                        rsq  += __shfl_xor(rsq, off);
                    }
                    if (l15 == 0) {
                        red[s * 16 + w * 2 + 0] = rsum;
                        red[s * 16 + w * 2 + 1] = rsq;
                    }
                }
            }
        }
        __syncthreads();
        if (tid < T_) {
            int s = tid;
            float S = 0.f, Q = 0.f;
            #pragma unroll
            for (int q = 0; q < 8; ++q) { S += red[s * 16 + q * 2]; Q += red[s * 16 + q * 2 + 1]; }
            float mu = S * (1.f / 512.f);
            float var = Q * (1.f / 512.f) - mu * mu;
            red[768 + s] = mu;
            red[816 + s] = rsqrtf(var + EPS_);
        }
        __syncthreads();

        // h -> hb (overlay repb; all repb reads done two barriers ago)
        unsigned short* hb = repb;
        float lg[4], lb[4];
        #pragma unroll
        for (int n = 0; n < 4; ++n) {
            int d = (4 * w + n) * 16 + l15;
            lg[n] = lnbg[d]; lb[n] = lnbb[d];
        }
        #pragma unroll
        for (int m = 0; m < 3; ++m) {
            #pragma unroll
            for (int j = 0; j < 4; ++j) {
                int s = m * 16 + l4 * 4 + j;
                if (s < T_) {
                    float mu = red[768 + s], rs = red[816 + s];
                    #pragma unroll
                    for (int n = 0; n < 4; ++n) {
                        int d = (4 * w + n) * 16 + l15;
                        hb[s * 520 + d] = f2bf((acc[m][n][j] - mu) * rs * lg[n] + lb[n]);
                    }
                }
            }
        }
    }
    __syncthreads();

    // ---- grouped down conv: z[o][s] = sum_c h[g*128+c][s] * wd[o][c] ----
    for (int idx = tid; idx < DS_ * T_; idx += 512) {
        int o = idx / T_, s = idx - o * T_;
        const unsigned short* hrow = repb + s * 520 + (o >> 3) * DG_;
        const float* wrow = wd + o * DG_;
        float accv = 0.f;
        #pragma unroll
        for (int c = 0; c < DG_; c += 8) {
            u16x8 hv = *(const u16x8*)&hrow[c];
            f32x4 w0 = *(const f32x4*)(wrow + c);
            f32x4 w1 = *(const f32x4*)(wrow + c + 4);
            accv += bf2f(hv[0])*w0[0] + bf2f(hv[1])*w0[1] + bf2f(hv[2])*w0[2] + bf2f(hv[3])*w0[3]
                  + bf2f(hv[4])*w1[0] + bf2f(hv[5])*w1[1] + bf2f(hv[6])*w1[2] + bf2f(hv[7])*w1[3];
        }
        z_pre[b * (DS_ * T_) + idx] = accv;
    }
}

// ---- K3: bn1 stats (per channel over B,T) ----
__global__ __launch_bounds__(256)
void k3_bn1stats(const float* __restrict__ z_pre, float* __restrict__ st1)
{
    __shared__ float rbuf[4][2];
    int o = blockIdx.x;
    int tid = threadIdx.x;
    float S = 0.f, Q = 0.f;
    for (int b = tid; b < B_; b += 256) {
        const float* p = z_pre + b * (DS_ * T_) + o * T_;
        #pragma unroll
        for (int t = 0; t < T_; ++t) { float v = p[t]; S += v; Q += v * v; }
    }
    #pragma unroll
    for (int off = 1; off < 64; off <<= 1) { S += __shfl_xor(S, off); Q += __shfl_xor(Q, off); }
    int w = tid >> 6, lane = tid & 63;
    if (lane == 0) { rbuf[w][0] = S; rbuf[w][1] = Q; }
    __syncthreads();
    if (tid == 0) {
        float s2 = 0.f, q2 = 0.f;
        for (int i = 0; i < 4; ++i) { s2 += rbuf[i][0]; q2 += rbuf[i][1]; }
        float mu = s2 / 36864.f;
        float var = q2 / 36864.f - mu * mu;
        st1[o] = mu; st1[32 + o] = rsqrtf(var + EPS_);
    }
}

// ---- K4: bn2 per-block partial stats (recompute up-conv on the fly) ----
__global__ __launch_bounds__(256)
void k4_bn2partials(const float* __restrict__ z_pre, const float* __restrict__ st1,
                    const float* __restrict__ g1p, const float* __restrict__ b1p,
                    const float* __restrict__ wu, float* __restrict__ partials)
{
    __shared__ float zrT[T_][40];
    int blk = blockIdx.x;
    int tid = threadIdx.x;
    int d0 = tid * 2;
    float w0[8], w1[8];
    #pragma unroll
    for (int c = 0; c < 8; ++c) { w0[c] = wu[d0 * 8 + c]; w1[c] = wu[(d0 + 1) * 8 + c]; }
    int g = d0 >> 7;
    float S0 = 0.f, Q0 = 0.f, S1 = 0.f, Q1 = 0.f;
    for (int bi = 0; bi < 4; ++bi) {
        int b = blk * 4 + bi;
        __syncthreads();
        for (int i = tid; i < DS_ * T_; i += 256) {
            int o = i / T_, s = i - o * T_;
            float v = z_pre[b * (DS_ * T_) + i];
            zrT[s][o] = fmaxf(0.f, (v - st1[o]) * st1[32 + o] * g1p[o] + b1p[o]);
        }
        __syncthreads();
        for (int t = 0; t < T_; ++t) {
            const float* zp = &zrT[t][g * 8];
            float o0 = 0.f, o1 = 0.f;
            #pragma unroll
            for (int c = 0; c < 8; ++c) { o0 += zp[c] * w0[c]; o1 += zp[c] * w1[c]; }
            S0 += o0; Q0 += o0 * o0; S1 += o1; Q1 += o1 * o1;
        }
    }
    float* pp = partials + blk * 1024;
    pp[d0 * 2 + 0] = S0; pp[d0 * 2 + 1] = Q0;
    pp[d0 * 2 + 2] = S1; pp[d0 * 2 + 3] = Q1;
}

__global__ __launch_bounds__(512)
void k4b_bn2stats(const float* __restrict__ partials, float* __restrict__ st2)
{
    int d = threadIdx.x;
    float S = 0.f, Q = 0.f;
    for (int blk = 0; blk < 256; ++blk) {
        S += partials[blk * 1024 + d * 2];
        Q += partials[blk * 1024 + d * 2 + 1];
    }
    float mu = S / 36864.f;
    float var = Q / 36864.f - mu * mu;
    st2[d] = mu; st2[512 + d] = rsqrtf(var + EPS_);
}

// ---- K5: up conv + bn2 + LN(lnp) + gate -> out ----
// dyn LDS: o_f [512][38] f32 @0 (77824) ; zrT [36][40] f32 @77824 (5760) ; wuL [4096] f32 @83584 (16384)
#define K5_LDS 99968
__global__ __launch_bounds__(256)
void k5_final(const float* __restrict__ z_pre, const float* __restrict__ st1,
              const float* __restrict__ g1p, const float* __restrict__ b1p,
              const float* __restrict__ wu, const float* __restrict__ st2,
              const float* __restrict__ g2p, const float* __restrict__ b2p,
              const float* __restrict__ lnpg, const float* __restrict__ lnpb,
              const float* __restrict__ gate_p, float* __restrict__ out)
{
    extern __shared__ char lds[];
    float* o_f = (float*)lds;             // [512][38]
    float* zrT = (float*)(lds + 77824);   // [36][40]
    float* wuL = (float*)(lds + 83584);   // [4096]
    int b = blockIdx.x;
    int tid = threadIdx.x;

    for (int i = tid; i < 4096; i += 256) wuL[i] = wu[i];
    for (int i = tid; i < DS_ * T_; i += 256) {
        int o = i / T_, s = i - o * T_;
        float v = z_pre[b * (DS_ * T_) + i];
        zrT[s * 40 + o] = fmaxf(0.f, (v - st1[o]) * st1[32 + o] * g1p[o] + b1p[o]);
    }
    __syncthreads();

    for (int i = tid; i < D_ * T_; i += 256) {
        int d = i / T_, t = i - d * T_;
        const float* zp = &zrT[t * 40 + (d >> 7) * 8];
        const float* wp = &wuL[d * 8];
        float acc = 0.f;
        #pragma unroll
        for (int c = 0; c < 8; ++c) acc += zp[c] * wp[c];
        o_f[d * 38 + t] = (acc - st2[d]) * st2[512 + d] * g2p[d] + b2p[d];
    }
    __syncthreads();

    int w = tid >> 6, lane = tid & 63;
    float gate = gate_p[0];
    for (int t = w; t < T_; t += 4) {
        float S = 0.f, Q = 0.f;
        float v[8];
        #pragma unroll
        for (int i2 = 0; i2 < 8; ++i2) {
            float vv = o_f[(i2 * 64 + lane) * 38 + t];
            v[i2] = vv; S += vv; Q += vv * vv;
        }
        #pragma unroll
        for (int off = 1; off < 64; off <<= 1) { S += __shfl_xor(S, off); Q += __shfl_xor(Q, off); }
        float mu = S * (1.f / 512.f);
        float var = Q * (1.f / 512.f) - mu * mu;
        float rs = rsqrtf(var + EPS_);
        #pragma unroll
        for (int i2 = 0; i2 < 8; ++i2) {
            int d = i2 * 64 + lane;
            o_f[d * 38 + t] = gate * ((v[i2] - mu) * rs * lnpg[d] + lnpb[d]);
        }
    }
    __syncthreads();

    float* ob = out + b * (D_ * T_);
    for (int i = tid; i < D_ * T_; i += 256) {
        int d = i / T_, t = i - d * T_;
        ob[i] = o_f[d * 38 + t];
    }
}

extern "C" void kernel_launch(void* const* d_in, const int* in_sizes, int n_in,
                              void* d_out, int out_size, void* d_ws, size_t ws_size,
                              hipStream_t stream)
{
    (void)in_sizes; (void)n_in; (void)out_size; (void)ws_size;
    const float* x    = (const float*)d_in[0];
    const float* y    = (const float*)d_in[1];
    const float* tok  = (const float*)d_in[2];
    const float* gate = (const float*)d_in[3];
    const float* gav  = (const float*)d_in[4];
    const float* wd   = (const float*)d_in[5];
    const float* wu   = (const float*)d_in[6];
    const float* bn1g = (const float*)d_in[7];
    const float* bn1b = (const float*)d_in[8];
    const float* bn2g = (const float*)d_in[9];
    const float* bn2b = (const float*)d_in[10];
    const float* lnbg = (const float*)d_in[11];
    const float* lnbb = (const float*)d_in[12];
    const float* lnpg = (const float*)d_in[13];
    const float* lnpb = (const float*)d_in[14];
    float* out = (float*)d_out;

    char* ws = (char*)d_ws;
    float* z_pre = (float*)ws;                 // 1,179,648 f32 (4,718,592 B)
    float* st1   = (float*)(ws + 4718592);     // 64 f32
    float* parts = (float*)(ws + 4719104);     // 256*1024 f32
    float* st2   = (float*)(ws + 5767680);     // 1024 f32

    hipFuncSetAttribute((const void*)k1_attn, hipFuncAttributeMaxDynamicSharedMemorySize, K1_LDS);
    hipFuncSetAttribute((const void*)k5_final, hipFuncAttributeMaxDynamicSharedMemorySize, K5_LDS);

    k1_attn<<<B_, 512, K1_LDS, stream>>>(x, y, tok, gav, wd, lnbg, lnbb, z_pre);
    k3_bn1stats<<<DS_, 256, 0, stream>>>(z_pre, st1);
    k4_bn2partials<<<256, 256, 0, stream>>>(z_pre, st1, bn1g, bn1b, wu, parts);
    k4b_bn2stats<<<1, 512, 0, stream>>>(parts, st2);
    k5_final<<<B_, 256, K5_LDS, stream>>>(z_pre, st1, bn1g, bn1b, wu, st2, bn2g, bn2b,
                                          lnpg, lnpb, gate, out);
}

// Round 2
// 298.036 us; speedup vs baseline: 1.0591x; 1.0591x over previous
//
#include <hip/hip_runtime.h>

#define B_ 1024
#define D_ 512
#define T_ 36
#define NT_ 64
#define DS_ 32
#define DG_ 128   // D/G
#define EPS_ 1e-5f

typedef float f32x4 __attribute__((ext_vector_type(4)));
typedef __bf16 bf16x8 __attribute__((ext_vector_type(8)));
typedef unsigned short u16x8 __attribute__((ext_vector_type(8)));

#define DEVI static __device__ __forceinline__

DEVI unsigned short f2bf(float f) {
    union { float f; unsigned u; } v; v.f = f;
    unsigned u = v.u;
    unsigned r = u + 0x7fffu + ((u >> 16) & 1u);   // RNE
    return (unsigned short)(r >> 16);
}
DEVI float bf2f(unsigned short h) {
    union { unsigned u; float f; } v; v.u = ((unsigned)h) << 16;
    return v.f;
}

// ---- K0: prepack tok to bf16 (row-major [64][512]) ----
__global__ __launch_bounds__(512)
void k0_tokpack(const float* __restrict__ tok, unsigned short* __restrict__ tokbf)
{
    int i = blockIdx.x * 512 + threadIdx.x;
    if (i < NT_ * D_) tokbf[i] = f2bf(tok[i]);
}

// ---- K1 LDS layout (bytes) ----
// ysT/xsT ushort [64][520] @ 0       (rows s; ys/xs transposed; rows 36..63 zero)
// repb    ushort [64][520] @ 66560   (rep rows t; h overlay after G4)
// sc      float  [64][40]  @ 133120  (red overlays sc during G4)
// att1    ushort [64][72]  @ 143360  (cols 36..63 zero)
// att2    ushort [48][72]  @ 152576
#define K1_LDS 159488

__global__ __launch_bounds__(1024)
void k1_attn(const float* __restrict__ x, const float* __restrict__ y,
             const unsigned short* __restrict__ tokbf, const float* __restrict__ gav_p,
             const float* __restrict__ wd, const float* __restrict__ lnbg,
             const float* __restrict__ lnbb, float* __restrict__ z_pre)
{
    extern __shared__ char lds[];
    unsigned short* ysT  = (unsigned short*)(lds);
    unsigned short* repb = (unsigned short*)(lds + 66560);
    float*          sc   = (float*)(lds + 133120);
    float*          red  = (float*)(lds + 133120);   // overlays sc (sc dead by G4)
    unsigned short* att1 = (unsigned short*)(lds + 143360);
    unsigned short* att2 = (unsigned short*)(lds + 152576);

    const int b    = blockIdx.x;
    const int tid  = threadIdx.x;
    const int lane = tid & 63;
    const int w    = tid >> 6;   // wave 0..15
    const int l15  = lane & 15;
    const int l4   = lane >> 4;  // 0..3

    const float* yb = y + b * (D_ * T_);
    const float* xb = x + b * (D_ * T_);

    // ---- P0: zero pads ----
    {
        unsigned* p = (unsigned*)(ysT + 36 * 520);
        for (int i = tid; i < (64 - 36) * 260; i += 1024) p[i] = 0u;
        unsigned* q = (unsigned*)att1;
        for (int i = tid; i < 64 * 36; i += 1024) q[i] = 0u;
    }
    // ---- stage ys transposed (f32x4 coalesced loads) ----
    for (int c = tid; c < (D_ * T_) / 4; c += 1024) {
        f32x4 v = *(const f32x4*)(yb + (c << 2));
        int idx = c << 2;
        int d = idx / T_;
        int s = idx - d * T_;
        #pragma unroll
        for (int j = 0; j < 4; ++j) {
            ysT[s * 520 + d] = f2bf(v[j]);
            if (++s == T_) { s = 0; ++d; }
        }
    }
    __syncthreads();

    // ---- G1: sc[t][s] = tok @ ys   (M=64,N=48,K=512) ----
    if (w < 12) {
        int mt = w & 3, nt = w >> 2;
        f32x4 acc = {0.f, 0.f, 0.f, 0.f};
        int t = mt * 16 + l15;
        for (int ks = 0; ks < 16; ++ks) {
            int k0 = ks * 32 + l4 * 8;
            bf16x8 af  = *(const bf16x8*)(tokbf + t * 512 + k0);
            bf16x8 bfv = *(const bf16x8*)&ysT[(nt * 16 + l15) * 520 + k0];
            acc = __builtin_amdgcn_mfma_f32_16x16x32_bf16(af, bfv, acc, 0, 0, 0);
        }
        int s = nt * 16 + l15;
        if (s < T_) {
            #pragma unroll
            for (int j = 0; j < 4; ++j)
                sc[(mt * 16 + l4 * 4 + j) * 40 + s] = acc[j];
        }
    }
    __syncthreads();

    // ---- softmax over s per t ----
    if (tid < NT_) {
        int t = tid;
        float m = -1e30f;
        for (int s = 0; s < T_; ++s) m = fmaxf(m, sc[t * 40 + s]);
        float sum = 0.f;
        for (int s = 0; s < T_; ++s) { float e = __expf(sc[t * 40 + s] - m); sc[t * 40 + s] = e; sum += e; }
        float inv = 1.f / sum;
        for (int s = 0; s < T_; ++s)
            att1[t * 72 + s] = f2bf(sc[t * 40 + s] * inv);
    }
    __syncthreads();

    // ---- G2: rep[t][d] = tok[t][d] + att1 @ ysT^T  (M=64,N=512,K=48->64) ----
    {
        int mt = w >> 2;
        bf16x8 a0 = *(const bf16x8*)&att1[(mt * 16 + l15) * 72 + l4 * 8];
        bf16x8 a1 = *(const bf16x8*)&att1[(mt * 16 + l15) * 72 + 32 + l4 * 8];
        int ntBase = (w & 3) * 8;
        for (int nt = ntBase; nt < ntBase + 8; ++nt) {
            int d = nt * 16 + l15;
            f32x4 acc = {0.f, 0.f, 0.f, 0.f};
            #pragma unroll
            for (int ks = 0; ks < 2; ++ks) {
                int sbase = ks * 32 + l4 * 8;
                union { bf16x8 v; unsigned short u[8]; } bfv;
                #pragma unroll
                for (int j = 0; j < 8; ++j)
                    bfv.u[j] = ysT[(sbase + j) * 520 + d];
                acc = __builtin_amdgcn_mfma_f32_16x16x32_bf16(ks ? a1 : a0, bfv.v, acc, 0, 0, 0);
            }
            #pragma unroll
            for (int j = 0; j < 4; ++j) {
                int tt = mt * 16 + l4 * 4 + j;
                repb[tt * 520 + d] = f2bf(bf2f(tokbf[tt * 512 + d]) + acc[j]);
            }
        }
    }
    __syncthreads();

    // ---- stage xs transposed (rows 36..63 stay zero) ----
    for (int c = tid; c < (D_ * T_) / 4; c += 1024) {
        f32x4 v = *(const f32x4*)(xb + (c << 2));
        int idx = c << 2;
        int d = idx / T_;
        int s = idx - d * T_;
        #pragma unroll
        for (int j = 0; j < 4; ++j) {
            ysT[s * 520 + d] = f2bf(v[j]);
            if (++s == T_) { s = 0; ++d; }
        }
    }
    __syncthreads();

    // ---- G3: sc[t][s] = rep @ xs   (M=64,N=48,K=512) ----
    if (w < 12) {
        int mt = w & 3, nt = w >> 2;
        f32x4 acc = {0.f, 0.f, 0.f, 0.f};
        for (int ks = 0; ks < 16; ++ks) {
            int k0 = ks * 32 + l4 * 8;
            bf16x8 af  = *(const bf16x8*)&repb[(mt * 16 + l15) * 520 + k0];
            bf16x8 bfv = *(const bf16x8*)&ysT[(nt * 16 + l15) * 520 + k0];
            acc = __builtin_amdgcn_mfma_f32_16x16x32_bf16(af, bfv, acc, 0, 0, 0);
        }
        int s = nt * 16 + l15;
        if (s < T_) {
            #pragma unroll
            for (int j = 0; j < 4; ++j)
                sc[(mt * 16 + l4 * 4 + j) * 40 + s] = acc[j];
        }
    }
    __syncthreads();

    // ---- softmax over t per s ----
    if (tid < T_) {
        int s = tid;
        float m = -1e30f;
        for (int t = 0; t < NT_; ++t) m = fmaxf(m, sc[t * 40 + s]);
        float sum = 0.f;
        for (int t = 0; t < NT_; ++t) { float e = __expf(sc[t * 40 + s] - m); sc[t * 40 + s] = e; sum += e; }
        float inv = 1.f / sum;
        for (int t = 0; t < NT_; ++t)
            att2[s * 72 + t] = f2bf(sc[t * 40 + s] * inv);
    }
    __syncthreads();

    // ---- G4: x_res[s][d] = att2 @ rep (M=48,N=512,K=64) + xc + LN -> h ----
    {
        const float gav = gav_p[0];
        f32x4 acc[3][2];
        f32x4 vzero = {0.f, 0.f, 0.f, 0.f};
        #pragma unroll
        for (int m = 0; m < 3; ++m)
            #pragma unroll
            for (int n = 0; n < 2; ++n) acc[m][n] = vzero;

        #pragma unroll
        for (int ks = 0; ks < 2; ++ks) {
            bf16x8 af[3];
            #pragma unroll
            for (int m = 0; m < 3; ++m)
                af[m] = *(const bf16x8*)&att2[(m * 16 + l15) * 72 + ks * 32 + l4 * 8];
            #pragma unroll
            for (int n = 0; n < 2; ++n) {
                int d = (2 * w + n) * 16 + l15;
                int tb = ks * 32 + l4 * 8;
                union { bf16x8 v; unsigned short u[8]; } bfv;
                #pragma unroll
                for (int j = 0; j < 8; ++j)
                    bfv.u[j] = repb[(tb + j) * 520 + d];
                #pragma unroll
                for (int m = 0; m < 3; ++m)
                    acc[m][n] = __builtin_amdgcn_mfma_f32_16x16x32_bf16(af[m], bfv.v, acc[m][n], 0, 0, 0);
            }
        }

        // xc = xs + gav*x_res ; per-s partial sums for LN (red overlays dead sc)
        #pragma unroll
        for (int m = 0; m < 3; ++m) {
            #pragma unroll
            for (int j = 0; j < 4; ++j) {
                int s = m * 16 + l4 * 4 + j;
                if (s < T_) {
                    float rsum = 0.f, rsq = 0.f;
                    #pragma unroll
                    for (int n = 0; n < 2; ++n) {
                        int d = (2 * w + n) * 16 + l15;
                        float xc = bf2f(ysT[s * 520 + d]) + gav * acc[m][n][j];
                        acc[m][n][j] = xc;
                        rsum += xc; rsq += xc * xc;
                    }
                    #pragma unroll
                    for (int off = 1; off < 16; off <<= 1) {
                        rsum += __shfl_xor(rsum, off);
                        rsq  += __shfl_xor(rsq, off);
                    }
                    if (l15 == 0) {
                        red[s * 32 + w * 2 + 0] = rsum;
                        red[s * 32 + w * 2 + 1] = rsq;
                    }
                }
            }
        }
        __syncthreads();
        if (tid < T_) {
            int s = tid;
            float S = 0.f, Q = 0.f;
            #pragma unroll
            for (int q = 0; q < 16; ++q) { S += red[s * 32 + q * 2]; Q += red[s * 32 + q * 2 + 1]; }
            float mu = S * (1.f / 512.f);
            float var = Q * (1.f / 512.f) - mu * mu;
            red[1152 + s] = mu;
            red[1200 + s] = rsqrtf(var + EPS_);
        }
        __syncthreads();

        // h -> repb overlay
        unsigned short* hb = repb;
        float lg[2], lb[2];
        #pragma unroll
        for (int n = 0; n < 2; ++n) {
            int d = (2 * w + n) * 16 + l15;
            lg[n] = lnbg[d]; lb[n] = lnbb[d];
        }
        #pragma unroll
        for (int m = 0; m < 3; ++m) {
            #pragma unroll
            for (int j = 0; j < 4; ++j) {
                int s = m * 16 + l4 * 4 + j;
                if (s < T_) {
                    float mu = red[1152 + s], rs = red[1200 + s];
                    #pragma unroll
                    for (int n = 0; n < 2; ++n) {
                        int d = (2 * w + n) * 16 + l15;
                        hb[s * 520 + d] = f2bf((acc[m][n][j] - mu) * rs * lg[n] + lb[n]);
                    }
                }
            }
        }
    }
    __syncthreads();

    // ---- grouped down conv: z[o][s] = sum_c h[g*128+c][s] * wd[o][c] ----
    for (int idx = tid; idx < DS_ * T_; idx += 1024) {
        int o = idx / T_, s = idx - o * T_;
        const unsigned short* hrow = repb + s * 520 + (o >> 3) * DG_;
        const float* wrow = wd + o * DG_;
        float accv = 0.f;
        #pragma unroll
        for (int c = 0; c < DG_; c += 8) {
            u16x8 hv = *(const u16x8*)&hrow[c];
            f32x4 w0 = *(const f32x4*)(wrow + c);
            f32x4 w1 = *(const f32x4*)(wrow + c + 4);
            accv += bf2f(hv[0])*w0[0] + bf2f(hv[1])*w0[1] + bf2f(hv[2])*w0[2] + bf2f(hv[3])*w0[3]
                  + bf2f(hv[4])*w1[0] + bf2f(hv[5])*w1[1] + bf2f(hv[6])*w1[2] + bf2f(hv[7])*w1[3];
        }
        z_pre[b * (DS_ * T_) + idx] = accv;
    }
}

// ---- K3: bn1 stats (per channel over B,T) ----
__global__ __launch_bounds__(256)
void k3_bn1stats(const float* __restrict__ z_pre, float* __restrict__ st1)
{
    __shared__ float rbuf[4][2];
    int o = blockIdx.x;
    int tid = threadIdx.x;
    float S = 0.f, Q = 0.f;
    for (int i = tid; i < B_ * T_; i += 256) {
        int b = i / T_, t = i - b * T_;
        float v = z_pre[b * (DS_ * T_) + o * T_ + t];
        S += v; Q += v * v;
    }
    #pragma unroll
    for (int off = 1; off < 64; off <<= 1) { S += __shfl_xor(S, off); Q += __shfl_xor(Q, off); }
    int w = tid >> 6, lane = tid & 63;
    if (lane == 0) { rbuf[w][0] = S; rbuf[w][1] = Q; }
    __syncthreads();
    if (tid == 0) {
        float s2 = 0.f, q2 = 0.f;
        for (int i = 0; i < 4; ++i) { s2 += rbuf[i][0]; q2 += rbuf[i][1]; }
        float mu = s2 / 36864.f;
        float var = q2 / 36864.f - mu * mu;
        st1[o] = mu; st1[32 + o] = rsqrtf(var + EPS_);
    }
}

// ---- K4: bn2 per-block partial stats (recompute up-conv on the fly) ----
// 128 blocks x 512 threads; each thread owns one d; 8 batches per block.
__global__ __launch_bounds__(512)
void k4_bn2partials(const float* __restrict__ z_pre, const float* __restrict__ st1,
                    const float* __restrict__ g1p, const float* __restrict__ b1p,
                    const float* __restrict__ wu, float* __restrict__ partials)
{
    __shared__ float zrT[T_][40];
    int blk = blockIdx.x;
    int d = threadIdx.x;
    float wreg[8];
    #pragma unroll
    for (int c = 0; c < 8; ++c) wreg[c] = wu[d * 8 + c];
    int g = d >> 7;
    float S = 0.f, Q = 0.f;
    for (int bi = 0; bi < 8; ++bi) {
        int b = blk * 8 + bi;
        __syncthreads();
        for (int i = d; i < DS_ * T_; i += 512) {
            int o = i / T_, s = i - o * T_;
            float v = z_pre[b * (DS_ * T_) + i];
            zrT[s][o] = fmaxf(0.f, (v - st1[o]) * st1[32 + o] * g1p[o] + b1p[o]);
        }
        __syncthreads();
        for (int t = 0; t < T_; ++t) {
            const float* zp = &zrT[t][g * 8];
            float o0 = 0.f;
            #pragma unroll
            for (int c = 0; c < 8; ++c) o0 += zp[c] * wreg[c];
            S += o0; Q += o0 * o0;
        }
    }
    float* pp = partials + blk * 1024;
    pp[d] = S; pp[512 + d] = Q;
}

__global__ __launch_bounds__(512)
void k4b_bn2stats(const float* __restrict__ partials, float* __restrict__ st2)
{
    int d = threadIdx.x;
    float S = 0.f, Q = 0.f;
    for (int blk = 0; blk < 128; ++blk) {
        S += partials[blk * 1024 + d];
        Q += partials[blk * 1024 + 512 + d];
    }
    float mu = S / 36864.f;
    float var = Q / 36864.f - mu * mu;
    st2[d] = mu; st2[512 + d] = rsqrtf(var + EPS_);
}

// ---- K5: up conv + bn2 + LN(lnp) + gate -> out ----
// dyn LDS: o_f [512][37] f32 @0 (75776) ; zrT [36][40] f32 @75776 (5760)  => 81536 (2 blocks/CU)
#define K5_LDS 81536
__global__ __launch_bounds__(512)
void k5_final(const float* __restrict__ z_pre, const float* __restrict__ st1,
              const float* __restrict__ g1p, const float* __restrict__ b1p,
              const float* __restrict__ wu, const float* __restrict__ st2,
              const float* __restrict__ g2p, const float* __restrict__ b2p,
              const float* __restrict__ lnpg, const float* __restrict__ lnpb,
              const float* __restrict__ gate_p, float* __restrict__ out)
{
    extern __shared__ char lds[];
    float* o_f = (float*)lds;             // [512][37]
    float* zrT = (float*)(lds + 75776);   // [36][40]
    int b = blockIdx.x;
    int tid = threadIdx.x;

    for (int i = tid; i < DS_ * T_; i += 512) {
        int o = i / T_, s = i - o * T_;
        float v = z_pre[b * (DS_ * T_) + i];
        zrT[s * 40 + o] = fmaxf(0.f, (v - st1[o]) * st1[32 + o] * g1p[o] + b1p[o]);
    }
    __syncthreads();

    for (int i = tid; i < D_ * T_; i += 512) {
        int d = i / T_, t = i - d * T_;
        const float* zp = &zrT[t * 40 + (d >> 7) * 8];
        const float* wp = &wu[d * 8];
        f32x4 w0 = *(const f32x4*)wp;
        f32x4 w1 = *(const f32x4*)(wp + 4);
        float acc = zp[0]*w0[0] + zp[1]*w0[1] + zp[2]*w0[2] + zp[3]*w0[3]
                  + zp[4]*w1[0] + zp[5]*w1[1] + zp[6]*w1[2] + zp[7]*w1[3];
        o_f[d * 37 + t] = (acc - st2[d]) * st2[512 + d] * g2p[d] + b2p[d];
    }
    __syncthreads();

    int w = tid >> 6, lane = tid & 63;
    float gate = gate_p[0];
    for (int t = w; t < T_; t += 8) {
        float S = 0.f, Q = 0.f;
        float v[8];
        #pragma unroll
        for (int i2 = 0; i2 < 8; ++i2) {
            float vv = o_f[(i2 * 64 + lane) * 37 + t];
            v[i2] = vv; S += vv; Q += vv * vv;
        }
        #pragma unroll
        for (int off = 1; off < 64; off <<= 1) { S += __shfl_xor(S, off); Q += __shfl_xor(Q, off); }
        float mu = S * (1.f / 512.f);
        float var = Q * (1.f / 512.f) - mu * mu;
        float rs = rsqrtf(var + EPS_);
        #pragma unroll
        for (int i2 = 0; i2 < 8; ++i2) {
            int d = i2 * 64 + lane;
            o_f[d * 37 + t] = gate * ((v[i2] - mu) * rs * lnpg[d] + lnpb[d]);
        }
    }
    __syncthreads();

    float* ob = out + b * (D_ * T_);
    for (int i = tid; i < D_ * T_; i += 512) {
        int d = i / T_, t = i - d * T_;
        ob[i] = o_f[d * 37 + t];
    }
}

extern "C" void kernel_launch(void* const* d_in, const int* in_sizes, int n_in,
                              void* d_out, int out_size, void* d_ws, size_t ws_size,
                              hipStream_t stream)
{
    (void)in_sizes; (void)n_in; (void)out_size; (void)ws_size;
    const float* x    = (const float*)d_in[0];
    const float* y    = (const float*)d_in[1];
    const float* tok  = (const float*)d_in[2];
    const float* gate = (const float*)d_in[3];
    const float* gav  = (const float*)d_in[4];
    const float* wd   = (const float*)d_in[5];
    const float* wu   = (const float*)d_in[6];
    const float* bn1g = (const float*)d_in[7];
    const float* bn1b = (const float*)d_in[8];
    const float* bn2g = (const float*)d_in[9];
    const float* bn2b = (const float*)d_in[10];
    const float* lnbg = (const float*)d_in[11];
    const float* lnbb = (const float*)d_in[12];
    const float* lnpg = (const float*)d_in[13];
    const float* lnpb = (const float*)d_in[14];
    float* out = (float*)d_out;

    char* ws = (char*)d_ws;
    float* z_pre          = (float*)ws;                  // 4,718,592 B
    float* st1            = (float*)(ws + 4718592);      // 64 f32 (+pad)
    unsigned short* tokbf = (unsigned short*)(ws + 4719104); // 65,536 B
    float* parts          = (float*)(ws + 4784640);      // 128*1024 f32 = 524,288 B
    float* st2            = (float*)(ws + 5308928);      // 1024 f32

    hipFuncSetAttribute((const void*)k1_attn, hipFuncAttributeMaxDynamicSharedMemorySize, K1_LDS);
    hipFuncSetAttribute((const void*)k5_final, hipFuncAttributeMaxDynamicSharedMemorySize, K5_LDS);

    k0_tokpack<<<64, 512, 0, stream>>>(tok, tokbf);
    k1_attn<<<B_, 1024, K1_LDS, stream>>>(x, y, tokbf, gav, wd, lnbg, lnbb, z_pre);
    k3_bn1stats<<<DS_, 256, 0, stream>>>(z_pre, st1);
    k4_bn2partials<<<128, 512, 0, stream>>>(z_pre, st1, bn1g, bn1b, wu, parts);
    k4b_bn2stats<<<1, 512, 0, stream>>>(parts, st2);
    k5_final<<<B_, 512, K5_LDS, stream>>>(z_pre, st1, bn1g, bn1b, wu, st2, bn2g, bn2b,
                                          lnpg, lnpb, gate, out);
}

// Round 3
// 237.109 us; speedup vs baseline: 1.3313x; 1.2570x over previous
//
#include <hip/hip_runtime.h>

#define B_ 1024
#define D_ 512
#define T_ 36
#define NT_ 64
#define DS_ 32
#define DG_ 128   // D/G
#define EPS_ 1e-5f

typedef float f32x4 __attribute__((ext_vector_type(4)));
typedef __bf16 bf16x8 __attribute__((ext_vector_type(8)));
typedef unsigned short u16x8 __attribute__((ext_vector_type(8)));

#define DEVI static __device__ __forceinline__

DEVI unsigned short f2bf(float f) {
    union { float f; unsigned u; } v; v.f = f;
    unsigned u = v.u;
    unsigned r = u + 0x7fffu + ((u >> 16) & 1u);   // RNE
    return (unsigned short)(r >> 16);
}
DEVI float bf2f(unsigned short h) {
    union { unsigned u; float f; } v; v.u = ((unsigned)h) << 16;
    return v.f;
}

// swizzled byte offset: row-major tile, 16B-slot XOR swizzle (T2 pattern)
DEVI unsigned swz(int row, int pitchB, int col) {   // col in elements (ushort)
    return (unsigned)(row * pitchB + ((2 * col) ^ ((row & 7) << 4)));
}

// ---- K0: prepack tok to bf16 (row-major [64][512]) ----
__global__ __launch_bounds__(512)
void k0_tokpack(const float* __restrict__ tok, unsigned short* __restrict__ tokbf)
{
    int i = blockIdx.x * 512 + threadIdx.x;
    if (i < NT_ * D_) tokbf[i] = f2bf(tok[i]);
}

// =================== K1A: stage ysT -> G1 -> softmax1 -> G2 -> rep(tiled, global) ===================
// LDS: ysT swz [48 rows][1024B] @0 (49152) ; sc f32 [64][42] @49152 (10752) ; att1 u16 [64][72] @59904 (9216)
#define K1A_LDS 69120
__global__ __launch_bounds__(1024, 8)
void k1a_attn(const float* __restrict__ y, const float* __restrict__ tokf,
              const unsigned short* __restrict__ tokbf,
              unsigned short* __restrict__ rep_g, int b0)
{
    extern __shared__ char lds[];
    float*          sc   = (float*)(lds + 49152);
    unsigned short* att1 = (unsigned short*)(lds + 59904);

    const int b    = b0 + blockIdx.x;
    const int tid  = threadIdx.x;
    const int lane = tid & 63;
    const int w    = tid >> 6;   // 0..15
    const int l15  = lane & 15;
    const int l4   = lane >> 4;  // 0..3

    const float* yb = y + b * (D_ * T_);
    unsigned short* repg = rep_g + (size_t)blockIdx.x * 32768;

    // zero att1 (64*72 u16 = 2304 dw) and ysT rows 36..47 (12*1024B = 3072 dw)
    for (int i = tid; i < 2304; i += 1024) ((unsigned*)att1)[i] = 0u;
    { unsigned* zp = (unsigned*)(lds + 36 * 1024);
      for (int i = tid; i < 3072; i += 1024) zp[i] = 0u; }

    // stage ysT swizzled: ysT[s][d] (bf16), byte = s*1024 + ((2d)^((s&7)<<4))
    for (int c = tid; c < (D_ * T_) / 4; c += 1024) {
        f32x4 v = *(const f32x4*)(yb + (c << 2));
        int idx = c << 2;
        int d = idx / T_, s = idx - d * T_;
        #pragma unroll
        for (int j = 0; j < 4; ++j) {
            *(unsigned short*)(lds + swz(s, 1024, d)) = f2bf(v[j]);
            if (++s == T_) { s = 0; ++d; }
        }
    }
    __syncthreads();

    // ---- G1: sc[t][s] = tok @ ys  (M=64,N=48,K=512) ----
    if (w < 12) {
        int mt = w & 3, nt = w >> 2;
        f32x4 acc = {0.f, 0.f, 0.f, 0.f};
        int t = mt * 16 + l15;
        int srow = nt * 16 + l15;
        for (int ks = 0; ks < 16; ++ks) {
            int k0 = ks * 32 + l4 * 8;
            bf16x8 af = *(const bf16x8*)(tokbf + t * 512 + k0);
            bf16x8 bv = *(const bf16x8*)(lds + swz(srow, 1024, k0));
            acc = __builtin_amdgcn_mfma_f32_16x16x32_bf16(af, bv, acc, 0, 0, 0);
        }
        int s = nt * 16 + l15;
        if (s < T_) {
            #pragma unroll
            for (int j = 0; j < 4; ++j)
                sc[(mt * 16 + l4 * 4 + j) * 42 + s] = acc[j];
        }
    }
    __syncthreads();

    // ---- softmax over s per t (quarter-wave parallel: t = tid>>4) ----
    {
        int t = tid >> 4, l16 = tid & 15;
        float v0 = sc[t * 42 + l16];
        float v1 = sc[t * 42 + l16 + 16];
        float v2 = (l16 < 4) ? sc[t * 42 + l16 + 32] : -1e30f;
        float m = fmaxf(fmaxf(v0, v1), v2);
        #pragma unroll
        for (int off = 1; off < 16; off <<= 1) m = fmaxf(m, __shfl_xor(m, off));
        float e0 = __expf(v0 - m), e1 = __expf(v1 - m);
        float e2 = (l16 < 4) ? __expf(v2 - m) : 0.f;
        float ssum = e0 + e1 + e2;
        #pragma unroll
        for (int off = 1; off < 16; off <<= 1) ssum += __shfl_xor(ssum, off);
        float inv = 1.f / ssum;
        att1[t * 72 + l16]      = f2bf(e0 * inv);
        att1[t * 72 + l16 + 16] = f2bf(e1 * inv);
        if (l16 < 4) att1[t * 72 + l16 + 32] = f2bf(e2 * inv);
    }
    __syncthreads();

    // ---- G2: rep[t][d] = tok + att1 @ ys^T  (K = s = 64 padded; B from GLOBAL y native layout) ----
    {
        int mt = w >> 2;
        int trow = mt * 16 + l15;
        bf16x8 a0 = *(const bf16x8*)&att1[trow * 72 + l4 * 8];
        bf16x8 a1 = *(const bf16x8*)&att1[trow * 72 + 32 + l4 * 8];
        int ntB = (w & 3) * 8;
        for (int nt = ntB; nt < ntB + 8; ++nt) {
            int d = nt * 16 + l15;
            const float* yrow = yb + d * T_;
            union { bf16x8 v; unsigned short u[8]; } fb0, fb1;
            f32x4 p0 = *(const f32x4*)(yrow + l4 * 8);
            f32x4 p1 = *(const f32x4*)(yrow + l4 * 8 + 4);
            #pragma unroll
            for (int j = 0; j < 4; ++j) { fb0.u[j] = f2bf(p0[j]); fb0.u[4 + j] = f2bf(p1[j]); }
            #pragma unroll
            for (int j = 0; j < 8; ++j) fb1.u[j] = 0;
            if (l4 == 0) {   // s=32..35 valid; 36..39 multiplied by zero att1
                f32x4 p2 = *(const f32x4*)(yrow + 32);
                #pragma unroll
                for (int j = 0; j < 4; ++j) { fb1.u[j] = f2bf(p2[j]); fb1.u[4 + j] = fb1.u[j]; }
            }
            f32x4 acc = {0.f, 0.f, 0.f, 0.f};
            acc = __builtin_amdgcn_mfma_f32_16x16x32_bf16(a0, fb0.v, acc, 0, 0, 0);
            acc = __builtin_amdgcn_mfma_f32_16x16x32_bf16(a1, fb1.v, acc, 0, 0, 0);
            // epilogue: + tok, write to tiled rep_g: tile=(mt*32+nt), [t%16][d%16]
            int tbase = (mt * 32 + nt) * 256;
            #pragma unroll
            for (int j = 0; j < 4; ++j) {
                int tt = mt * 16 + l4 * 4 + j;
                float val = tokf[tt * 512 + d] + acc[j];
                repg[tbase + (l4 * 4 + j) * 16 + l15] = f2bf(val);
            }
        }
    }
}

// =================== K1B: stage xsT,repT -> G3 -> softmax2 -> G4 -> LN -> downconv ===================
// LDS: repT swz [512 rows][128B] @0 (65536; h overlay [36][1024B] after G4)
//      xsT swz [48][1024B] @65536 (49152) ; sc f32 [64][42] @114688 (10752; red overlay)
//      att2 u16 [48][72] @125440 (6912)
#define K1B_LDS 132352
__global__ __launch_bounds__(1024, 4)
void k1b_attn(const float* __restrict__ x, const unsigned short* __restrict__ rep_g,
              const float* __restrict__ gav_p, const float* __restrict__ wd,
              const float* __restrict__ lnbg, const float* __restrict__ lnbb,
              float* __restrict__ z_pre, int b0)
{
    extern __shared__ char lds[];
    char*           xsl  = lds + 65536;
    float*          sc   = (float*)(lds + 114688);
    float*          red  = sc;
    unsigned short* att2 = (unsigned short*)(lds + 125440);

    const int b    = b0 + blockIdx.x;
    const int tid  = threadIdx.x;
    const int lane = tid & 63;
    const int w    = tid >> 6;
    const int l15  = lane & 15;
    const int l4   = lane >> 4;

    const float* xb = x + b * (D_ * T_);
    const unsigned short* repg = rep_g + (size_t)blockIdx.x * 32768;

    // zero att2 (48*72 u16 = 1728 dw) and xsT rows 36..47
    for (int i = tid; i < 1728; i += 1024) ((unsigned*)att2)[i] = 0u;
    { unsigned* zp = (unsigned*)(xsl + 36 * 1024);
      for (int i = tid; i < 3072; i += 1024) zp[i] = 0u; }

    // stage xsT swizzled
    for (int c = tid; c < (D_ * T_) / 4; c += 1024) {
        f32x4 v = *(const f32x4*)(xb + (c << 2));
        int idx = c << 2;
        int d = idx / T_, s = idx - d * T_;
        #pragma unroll
        for (int j = 0; j < 4; ++j) {
            *(unsigned short*)(xsl + swz(s, 1024, d)) = f2bf(v[j]);
            if (++s == T_) { s = 0; ++d; }
        }
    }
    // stage repT swizzled from tiled rep_g: repT[d][t], byte = d*128 + ((2t)^((d&7)<<4))
    #pragma unroll
    for (int it = 0; it < 4; ++it) {
        int lin = it * 1024 + tid;
        u16x8 v = *(const u16x8*)(repg + lin * 8);
        int tileidx = lin >> 5;
        int mt = tileidx >> 5, dt = tileidx & 31;
        int t = mt * 16 + ((lin & 31) >> 1);
        int d0 = dt * 16 + (lin & 1) * 8;
        #pragma unroll
        for (int c = 0; c < 8; ++c)
            *(unsigned short*)(lds + swz(d0 + c, 128, t)) = v[c];
    }
    __syncthreads();

    // ---- G3: sc[t][s] = rep @ xs  (M=64,N=48,K=512); A from tiled rep_g (global) ----
    if (w < 12) {
        int mt = w & 3, nt = w >> 2;
        f32x4 acc = {0.f, 0.f, 0.f, 0.f};
        int srow = nt * 16 + l15;
        for (int ks = 0; ks < 16; ++ks) {
            int tile = mt * 32 + ks * 2 + (l4 >> 1);
            bf16x8 af = *(const bf16x8*)(repg + tile * 256 + l15 * 16 + (l4 & 1) * 8);
            int k0 = ks * 32 + l4 * 8;
            bf16x8 bv = *(const bf16x8*)(xsl + swz(srow, 1024, k0));
            acc = __builtin_amdgcn_mfma_f32_16x16x32_bf16(af, bv, acc, 0, 0, 0);
        }
        int s = nt * 16 + l15;
        if (s < T_) {
            #pragma unroll
            for (int j = 0; j < 4; ++j)
                sc[(mt * 16 + l4 * 4 + j) * 42 + s] = acc[j];
        }
    }
    __syncthreads();

    // ---- softmax over t per s (quarter-wave: s = tid>>4, tid<576) ----
    if (tid < 576) {
        int s = tid >> 4, l16 = tid & 15;
        float v0 = sc[(l16     ) * 42 + s];
        float v1 = sc[(l16 + 16) * 42 + s];
        float v2 = sc[(l16 + 32) * 42 + s];
        float v3 = sc[(l16 + 48) * 42 + s];
        float m = fmaxf(fmaxf(v0, v1), fmaxf(v2, v3));
        #pragma unroll
        for (int off = 1; off < 16; off <<= 1) m = fmaxf(m, __shfl_xor(m, off));
        float e0 = __expf(v0 - m), e1 = __expf(v1 - m), e2 = __expf(v2 - m), e3 = __expf(v3 - m);
        float ssum = e0 + e1 + e2 + e3;
        #pragma unroll
        for (int off = 1; off < 16; off <<= 1) ssum += __shfl_xor(ssum, off);
        float inv = 1.f / ssum;
        att2[s * 72 + l16]      = f2bf(e0 * inv);
        att2[s * 72 + l16 + 16] = f2bf(e1 * inv);
        att2[s * 72 + l16 + 32] = f2bf(e2 * inv);
        att2[s * 72 + l16 + 48] = f2bf(e3 * inv);
    }
    __syncthreads();

    // ---- G4: x_res[s][d] = att2 @ repT (M=48,N=512,K=64) + xc + LN -> h ----
    {
        const float gav = gav_p[0];
        f32x4 acc[3][2];
        #pragma unroll
        for (int m = 0; m < 3; ++m)
            #pragma unroll
            for (int n = 0; n < 2; ++n) acc[m][n] = (f32x4){0.f, 0.f, 0.f, 0.f};

        #pragma unroll
        for (int ks = 0; ks < 2; ++ks) {
            int t0 = ks * 32 + l4 * 8;
            bf16x8 af[3];
            #pragma unroll
            for (int m = 0; m < 3; ++m)
                af[m] = *(const bf16x8*)&att2[(m * 16 + l15) * 72 + t0];
            #pragma unroll
            for (int n = 0; n < 2; ++n) {
                int d = (2 * w + n) * 16 + l15;
                bf16x8 bv = *(const bf16x8*)(lds + swz(d, 128, t0));
                #pragma unroll
                for (int m = 0; m < 3; ++m)
                    acc[m][n] = __builtin_amdgcn_mfma_f32_16x16x32_bf16(af[m], bv, acc[m][n], 0, 0, 0);
            }
        }

        // xc = xs + gav*x_res ; per-s LN partials
        #pragma unroll
        for (int m = 0; m < 3; ++m) {
            #pragma unroll
            for (int j = 0; j < 4; ++j) {
                int s = m * 16 + l4 * 4 + j;
                if (s < T_) {
                    float rsum = 0.f, rsq = 0.f;
                    #pragma unroll
                    for (int n = 0; n < 2; ++n) {
                        int d = (2 * w + n) * 16 + l15;
                        float xsv = bf2f(*(const unsigned short*)(xsl + swz(s, 1024, d)));
                        float xc = xsv + gav * acc[m][n][j];
                        acc[m][n][j] = xc;
                        rsum += xc; rsq += xc * xc;
                    }
                    #pragma unroll
                    for (int off = 1; off < 16; off <<= 1) {
                        rsum += __shfl_xor(rsum, off);
                        rsq  += __shfl_xor(rsq, off);
                    }
                    if (l15 == 0) {
                        red[s * 32 + w * 2 + 0] = rsum;
                        red[s * 32 + w * 2 + 1] = rsq;
                    }
                }
            }
        }
        __syncthreads();   // also: all repT reads done before h overlay
        if (tid < T_) {
            int s = tid;
            float S = 0.f, Q = 0.f;
            #pragma unroll
            for (int q = 0; q < 16; ++q) { S += red[s * 32 + q * 2]; Q += red[s * 32 + q * 2 + 1]; }
            float mu = S * (1.f / 512.f);
            float var = Q * (1.f / 512.f) - mu * mu;
            red[1152 + s] = mu;
            red[1200 + s] = rsqrtf(var + EPS_);
        }
        __syncthreads();

        // h (LN output, bf16) -> overlay repT region, swz rows [36][1024B]
        float lg[2], lb[2];
        #pragma unroll
        for (int n = 0; n < 2; ++n) {
            int d = (2 * w + n) * 16 + l15;
            lg[n] = lnbg[d]; lb[n] = lnbb[d];
        }
        #pragma unroll
        for (int m = 0; m < 3; ++m) {
            #pragma unroll
            for (int j = 0; j < 4; ++j) {
                int s = m * 16 + l4 * 4 + j;
                if (s < T_) {
                    float mu = red[1152 + s], rs = red[1200 + s];
                    #pragma unroll
                    for (int n = 0; n < 2; ++n) {
                        int d = (2 * w + n) * 16 + l15;
                        *(unsigned short*)(lds + swz(s, 1024, d)) =
                            f2bf((acc[m][n][j] - mu) * rs * lg[n] + lb[n]);
                    }
                }
            }
        }
    }
    __syncthreads();

    // ---- grouped down conv from h-swz ----
    for (int idx = tid; idx < DS_ * T_; idx += 1024) {
        int o = idx / T_, s = idx - o * T_;
        int goff = (o >> 3) * DG_;
        const float* wrow = wd + o * DG_;
        float accv = 0.f;
        #pragma unroll
        for (int c = 0; c < DG_; c += 8) {
            u16x8 hv = *(const u16x8*)(lds + swz(s, 1024, goff + c));
            f32x4 w0 = *(const f32x4*)(wrow + c);
            f32x4 w1 = *(const f32x4*)(wrow + c + 4);
            accv += bf2f(hv[0])*w0[0] + bf2f(hv[1])*w0[1] + bf2f(hv[2])*w0[2] + bf2f(hv[3])*w0[3]
                  + bf2f(hv[4])*w1[0] + bf2f(hv[5])*w1[1] + bf2f(hv[6])*w1[2] + bf2f(hv[7])*w1[3];
        }
        z_pre[b * (DS_ * T_) + idx] = accv;
    }
}

// ---- K3: bn1 stats, two-level ----
__global__ __launch_bounds__(256)
void k3a_bn1part(const float* __restrict__ z_pre, float* __restrict__ p3)
{
    __shared__ float rbuf[4][2];
    int blk = blockIdx.x;
    int o = blk & 31, sl = blk >> 5;
    int tid = threadIdx.x;
    float S = 0.f, Q = 0.f;
    for (int i = tid; i < 64 * T_; i += 256) {
        int bb = sl * 64 + i / T_, t = i - (i / T_) * T_;
        float v = z_pre[bb * (DS_ * T_) + o * T_ + t];
        S += v; Q += v * v;
    }
    #pragma unroll
    for (int off = 1; off < 64; off <<= 1) { S += __shfl_xor(S, off); Q += __shfl_xor(Q, off); }
    int ww = tid >> 6;
    if ((tid & 63) == 0) { rbuf[ww][0] = S; rbuf[ww][1] = Q; }
    __syncthreads();
    if (tid == 0) {
        float s2 = 0.f, q2 = 0.f;
        for (int i = 0; i < 4; ++i) { s2 += rbuf[i][0]; q2 += rbuf[i][1]; }
        p3[blk * 2] = s2; p3[blk * 2 + 1] = q2;
    }
}

__global__ __launch_bounds__(64)
void k3b_bn1stats(const float* __restrict__ p3, float* __restrict__ st1)
{
    int o = threadIdx.x;
    if (o < 32) {
        float S = 0.f, Q = 0.f;
        for (int sl = 0; sl < 16; ++sl) {
            S += p3[((sl << 5) | o) * 2];
            Q += p3[((sl << 5) | o) * 2 + 1];
        }
        float mu = S / 36864.f;
        float var = Q / 36864.f - mu * mu;
        st1[o] = mu; st1[32 + o] = rsqrtf(var + EPS_);
    }
}

// ---- K4: bn2 per-block partial stats (recompute up-conv) ----
__global__ __launch_bounds__(512)
void k4_bn2partials(const float* __restrict__ z_pre, const float* __restrict__ st1,
                    const float* __restrict__ g1p, const float* __restrict__ b1p,
                    const float* __restrict__ wu, float* __restrict__ partials)
{
    __shared__ float zrT[T_][41];
    int blk = blockIdx.x;
    int d = threadIdx.x;
    float wreg[8];
    #pragma unroll
    for (int c = 0; c < 8; ++c) wreg[c] = wu[d * 8 + c];
    int g = d >> 7;
    float S = 0.f, Q = 0.f;
    for (int bi = 0; bi < 4; ++bi) {
        int bb = blk * 4 + bi;
        __syncthreads();
        for (int i = d; i < DS_ * T_; i += 512) {
            int o = i / T_, s = i - o * T_;
            float v = z_pre[bb * (DS_ * T_) + i];
            zrT[s][o] = fmaxf(0.f, (v - st1[o]) * st1[32 + o] * g1p[o] + b1p[o]);
        }
        __syncthreads();
        for (int t = 0; t < T_; ++t) {
            const float* zp = &zrT[t][g * 8];
            float o0 = 0.f;
            #pragma unroll
            for (int c = 0; c < 8; ++c) o0 += zp[c] * wreg[c];
            S += o0; Q += o0 * o0;
        }
    }
    float* pp = partials + blk * 1024;
    pp[d] = S; pp[512 + d] = Q;
}

__global__ __launch_bounds__(512)
void k4b_bn2stats(const float* __restrict__ partials, float* __restrict__ st2)
{
    int d = threadIdx.x;
    float S = 0.f, Q = 0.f;
    for (int blk = 0; blk < 256; ++blk) {
        S += partials[blk * 1024 + d];
        Q += partials[blk * 1024 + 512 + d];
    }
    float mu = S / 36864.f;
    float var = Q / 36864.f - mu * mu;
    st2[d] = mu; st2[512 + d] = rsqrtf(var + EPS_);
}

// ---- K5: up conv + bn2 + LN(lnp) + gate -> out ----
// LDS: o_f u16 [512][41] @0 (41984) ; zrT f32 [36][41] @41984 (5904) => 47888 (3 blocks/CU)
#define K5_LDS 47888
__global__ __launch_bounds__(512, 6)
void k5_final(const float* __restrict__ z_pre, const float* __restrict__ st1,
              const float* __restrict__ g1p, const float* __restrict__ b1p,
              const float* __restrict__ wu, const float* __restrict__ st2,
              const float* __restrict__ g2p, const float* __restrict__ b2p,
              const float* __restrict__ lnpg, const float* __restrict__ lnpb,
              const float* __restrict__ gate_p, float* __restrict__ out)
{
    extern __shared__ char lds[];
    unsigned short* o_f = (unsigned short*)lds;   // [512][41]
    float* zrT = (float*)(lds + 41984);           // [36][41]
    int b = blockIdx.x;
    int tid = threadIdx.x;

    for (int i = tid; i < DS_ * T_; i += 512) {
        int o = i / T_, s = i - o * T_;
        float v = z_pre[b * (DS_ * T_) + i];
        zrT[s * 41 + o] = fmaxf(0.f, (v - st1[o]) * st1[32 + o] * g1p[o] + b1p[o]);
    }
    __syncthreads();

    for (int i = tid; i < D_ * T_; i += 512) {
        int d = i / T_, t = i - d * T_;
        const float* zp = &zrT[t * 41 + (d >> 7) * 8];
        const float* wp = &wu[d * 8];
        f32x4 w0 = *(const f32x4*)wp;
        f32x4 w1 = *(const f32x4*)(wp + 4);
        float acc = zp[0]*w0[0] + zp[1]*w0[1] + zp[2]*w0[2] + zp[3]*w0[3]
                  + zp[4]*w1[0] + zp[5]*w1[1] + zp[6]*w1[2] + zp[7]*w1[3];
        o_f[d * 41 + t] = f2bf((acc - st2[d]) * st2[512 + d] * g2p[d] + b2p[d]);
    }
    __syncthreads();

    int w = tid >> 6, lane = tid & 63;
    float gate = gate_p[0];
    for (int t = w; t < T_; t += 8) {
        float S = 0.f, Q = 0.f;
        float v[8];
        #pragma unroll
        for (int i2 = 0; i2 < 8; ++i2) {
            float vv = bf2f(o_f[(i2 * 64 + lane) * 41 + t]);
            v[i2] = vv; S += vv; Q += vv * vv;
        }
        #pragma unroll
        for (int off = 1; off < 64; off <<= 1) { S += __shfl_xor(S, off); Q += __shfl_xor(Q, off); }
        float mu = S * (1.f / 512.f);
        float var = Q * (1.f / 512.f) - mu * mu;
        float rs = rsqrtf(var + EPS_);
        #pragma unroll
        for (int i2 = 0; i2 < 8; ++i2) {
            int d = i2 * 64 + lane;
            o_f[d * 41 + t] = f2bf(gate * ((v[i2] - mu) * rs * lnpg[d] + lnpb[d]));
        }
    }
    __syncthreads();

    float* ob = out + b * (D_ * T_);
    for (int i = tid; i < D_ * T_; i += 512) {
        int d = i / T_, t = i - d * T_;
        ob[i] = bf2f(o_f[d * 41 + t]);
    }
}

extern "C" void kernel_launch(void* const* d_in, const int* in_sizes, int n_in,
                              void* d_out, int out_size, void* d_ws, size_t ws_size,
                              hipStream_t stream)
{
    (void)in_sizes; (void)n_in; (void)out_size;
    const float* x    = (const float*)d_in[0];
    const float* y    = (const float*)d_in[1];
    const float* tok  = (const float*)d_in[2];
    const float* gate = (const float*)d_in[3];
    const float* gav  = (const float*)d_in[4];
    const float* wd   = (const float*)d_in[5];
    const float* wu   = (const float*)d_in[6];
    const float* bn1g = (const float*)d_in[7];
    const float* bn1b = (const float*)d_in[8];
    const float* bn2g = (const float*)d_in[9];
    const float* bn2b = (const float*)d_in[10];
    const float* lnbg = (const float*)d_in[11];
    const float* lnbb = (const float*)d_in[12];
    const float* lnpg = (const float*)d_in[13];
    const float* lnpb = (const float*)d_in[14];
    float* out = (float*)d_out;

    char* ws = (char*)d_ws;
    float* z_pre          = (float*)ws;                      // 4,718,592
    float* st1            = (float*)(ws + 4718592);          // 512 B
    unsigned short* tokbf = (unsigned short*)(ws + 4719104); // 65,536
    float* parts          = (float*)(ws + 4784640);          // 1,048,576
    float* st2            = (float*)(ws + 5833216);          // 4,096
    float* p3             = (float*)(ws + 5837312);          // 4,096
    unsigned short* rep_g = (unsigned short*)(ws + 5841408); // chunked rep buffer

    // how many batches of rep (64KB each) fit in remaining ws
    size_t avail = (ws_size > 5841408) ? (ws_size - 5841408) : 65536;
    int bchunk = (int)(avail / 65536);
    if (bchunk < 1) bchunk = 1;
    if (bchunk > B_) bchunk = B_;

    hipFuncSetAttribute((const void*)k1a_attn, hipFuncAttributeMaxDynamicSharedMemorySize, K1A_LDS);
    hipFuncSetAttribute((const void*)k1b_attn, hipFuncAttributeMaxDynamicSharedMemorySize, K1B_LDS);

    k0_tokpack<<<64, 512, 0, stream>>>(tok, tokbf);
    for (int b0 = 0; b0 < B_; b0 += bchunk) {
        int cnt = (b0 + bchunk <= B_) ? bchunk : (B_ - b0);
        k1a_attn<<<cnt, 1024, K1A_LDS, stream>>>(y, tok, tokbf, rep_g, b0);
        k1b_attn<<<cnt, 1024, K1B_LDS, stream>>>(x, rep_g, gav, wd, lnbg, lnbb, z_pre, b0);
    }
    k3a_bn1part<<<512, 256, 0, stream>>>(z_pre, p3);
    k3b_bn1stats<<<1, 64, 0, stream>>>(p3, st1);
    k4_bn2partials<<<256, 512, 0, stream>>>(z_pre, st1, bn1g, bn1b, wu, parts);
    k4b_bn2stats<<<1, 512, 0, stream>>>(parts, st2);
    k5_final<<<B_, 512, K5_LDS, stream>>>(z_pre, st1, bn1g, bn1b, wu, st2, bn2g, bn2b,
                                          lnpg, lnpb, gate, out);
}